// Round 5
// baseline (123.210 us; speedup 1.0000x reference)
//
#include <hip/hip_runtime.h>
#include <math.h>

#define TT 2048
#define LK 769
#define NF 20
#define NS 128
#define NB 18
#define NFFT 4096

// tw3 group offsets (in 4-float2 groups) per Q level
#define TW3_Q4   0
#define TW3_Q8   4
#define TW3_Q32  12
#define TW3_Q64  44
#define TW3_Q256 108
#define TW3_Q512 364
#define TW3_TOT  876

typedef __attribute__((ext_vector_type(8))) short short8;
typedef __attribute__((ext_vector_type(4))) float f32x4;
typedef __attribute__((ext_vector_type(4))) unsigned short us4;

__device__ __forceinline__ float2 cmul(float2 a, float2 b) {
  return make_float2(a.x * b.x - a.y * b.y, a.x * b.y + a.y * b.x);
}
__device__ __forceinline__ float2 cmulc(float2 a, float2 b) {  // a * conj(b)
  return make_float2(a.x * b.x + a.y * b.y, a.y * b.x - a.x * b.y);
}
#define CADD(a, b) make_float2((a).x + (b).x, (a).y + (b).y)
#define CSUB(a, b) make_float2((a).x - (b).x, (a).y - (b).y)

// ---------------------------------------------------------------------------
// Radix-8 DIF forward stage (generic j). W3/5/6/7 from precomputed tw3 table.
// ---------------------------------------------------------------------------
__device__ __forceinline__ void fwd_r8(float2* z, const float2* __restrict__ tw,
                                       const float2* __restrict__ tw3q,
                                       int tt, int Q) {
  const float C = 0.70710678118654752f;
  const int j = tt & (Q - 1);
  const int base = ((tt & ~(Q - 1)) << 3) + j;
  const float2 x0 = z[base],         x1 = z[base + Q];
  const float2 x2 = z[base + 2 * Q], x3 = z[base + 3 * Q];
  const float2 x4 = z[base + 4 * Q], x5 = z[base + 5 * Q];
  const float2 x6 = z[base + 6 * Q], x7 = z[base + 7 * Q];
  const float2 W1 = tw[4 * Q + j], W2 = tw[2 * Q + j], W4 = tw[Q + j];
  const float4 w35 = *(const float4*)(tw3q + 4 * j);
  const float4 w67 = *(const float4*)(tw3q + 4 * j + 2);
  const float2 W3 = make_float2(w35.x, w35.y);
  const float2 W5 = make_float2(w35.z, w35.w);
  const float2 W6 = make_float2(w67.x, w67.y);
  const float2 W7 = make_float2(w67.z, w67.w);
  const float2 s0 = CADD(x0, x4), s1 = CSUB(x0, x4);
  const float2 s2 = CADD(x2, x6), s3 = CSUB(x2, x6);
  const float2 E0 = CADD(s0, s2), E2 = CSUB(s0, s2);
  const float2 E1 = make_float2(s1.x + s3.y, s1.y - s3.x);
  const float2 E3 = make_float2(s1.x - s3.y, s1.y + s3.x);
  const float2 t0 = CADD(x1, x5), t1 = CSUB(x1, x5);
  const float2 t2 = CADD(x3, x7), t3 = CSUB(x3, x7);
  const float2 O0 = CADD(t0, t2), O2 = CSUB(t0, t2);
  const float2 O1 = make_float2(t1.x + t3.y, t1.y - t3.x);
  const float2 O3 = make_float2(t1.x - t3.y, t1.y + t3.x);
  const float2 wO1 = make_float2(C * (O1.x + O1.y), C * (O1.y - O1.x));
  const float2 w3O3 = make_float2(C * (O3.y - O3.x), -C * (O3.x + O3.y));
  const float2 mO2 = make_float2(O2.y, -O2.x);
  const float2 y0 = CADD(E0, O0), y4 = CSUB(E0, O0);
  const float2 y1 = CADD(E1, wO1), y5 = CSUB(E1, wO1);
  const float2 y2 = CADD(E2, mO2), y6 = CSUB(E2, mO2);
  const float2 y3 = CADD(E3, w3O3), y7 = CSUB(E3, w3O3);
  z[base]         = y0;
  z[base + Q]     = cmul(y1, W1);
  z[base + 2 * Q] = cmul(y2, W2);
  z[base + 3 * Q] = cmul(y3, W3);
  z[base + 4 * Q] = cmul(y4, W4);
  z[base + 5 * Q] = cmul(y5, W5);
  z[base + 6 * Q] = cmul(y6, W6);
  z[base + 7 * Q] = cmul(y7, W7);
}

// Forward radix-8 stage specialized for Q=1 (j=0 -> all twiddles = 1).
__device__ __forceinline__ void fwd_r8_j0(float2* z, int base) {
  const float C = 0.70710678118654752f;
  const float2 x0 = z[base],     x1 = z[base + 1];
  const float2 x2 = z[base + 2], x3 = z[base + 3];
  const float2 x4 = z[base + 4], x5 = z[base + 5];
  const float2 x6 = z[base + 6], x7 = z[base + 7];
  const float2 s0 = CADD(x0, x4), s1 = CSUB(x0, x4);
  const float2 s2 = CADD(x2, x6), s3 = CSUB(x2, x6);
  const float2 E0 = CADD(s0, s2), E2 = CSUB(s0, s2);
  const float2 E1 = make_float2(s1.x + s3.y, s1.y - s3.x);
  const float2 E3 = make_float2(s1.x - s3.y, s1.y + s3.x);
  const float2 t0 = CADD(x1, x5), t1 = CSUB(x1, x5);
  const float2 t2 = CADD(x3, x7), t3 = CSUB(x3, x7);
  const float2 O0 = CADD(t0, t2), O2 = CSUB(t0, t2);
  const float2 O1 = make_float2(t1.x + t3.y, t1.y - t3.x);
  const float2 O3 = make_float2(t1.x - t3.y, t1.y + t3.x);
  const float2 wO1 = make_float2(C * (O1.x + O1.y), C * (O1.y - O1.x));
  const float2 w3O3 = make_float2(C * (O3.y - O3.x), -C * (O3.x + O3.y));
  const float2 mO2 = make_float2(O2.y, -O2.x);
  z[base]     = CADD(E0, O0);
  z[base + 4] = CSUB(E0, O0);
  z[base + 1] = CADD(E1, wO1);
  z[base + 5] = CSUB(E1, wO1);
  z[base + 2] = CADD(E2, mO2);
  z[base + 6] = CSUB(E2, mO2);
  z[base + 3] = CADD(E3, w3O3);
  z[base + 7] = CSUB(E3, w3O3);
}

// Radix-8 inverse stage (generic j), mirror of fwd.
__device__ __forceinline__ void inv_r8(float2* z, const float2* __restrict__ tw,
                                       const float2* __restrict__ tw3q,
                                       int tt, int Q) {
  const float C = 0.70710678118654752f;
  const int j = tt & (Q - 1);
  const int base = ((tt & ~(Q - 1)) << 3) + j;
  const float2 W1 = tw[4 * Q + j], W2 = tw[2 * Q + j], W4 = tw[Q + j];
  const float4 w35 = *(const float4*)(tw3q + 4 * j);
  const float4 w67 = *(const float4*)(tw3q + 4 * j + 2);
  const float2 W3 = make_float2(w35.x, w35.y);
  const float2 W5 = make_float2(w35.z, w35.w);
  const float2 W6 = make_float2(w67.x, w67.y);
  const float2 W7 = make_float2(w67.z, w67.w);
  const float2 u0 = z[base];
  const float2 u1 = cmulc(z[base + Q], W1);
  const float2 u2 = cmulc(z[base + 2 * Q], W2);
  const float2 u3 = cmulc(z[base + 3 * Q], W3);
  const float2 u4 = cmulc(z[base + 4 * Q], W4);
  const float2 u5 = cmulc(z[base + 5 * Q], W5);
  const float2 u6 = cmulc(z[base + 6 * Q], W6);
  const float2 u7 = cmulc(z[base + 7 * Q], W7);
  const float2 s0 = CADD(u0, u4), s1 = CSUB(u0, u4);
  const float2 s2 = CADD(u2, u6), s3 = CSUB(u2, u6);
  const float2 E0 = CADD(s0, s2), E2 = CSUB(s0, s2);
  const float2 E1 = make_float2(s1.x - s3.y, s1.y + s3.x);
  const float2 E3 = make_float2(s1.x + s3.y, s1.y - s3.x);
  const float2 t0 = CADD(u1, u5), t1 = CSUB(u1, u5);
  const float2 t2 = CADD(u3, u7), t3 = CSUB(u3, u7);
  const float2 O0 = CADD(t0, t2), O2 = CSUB(t0, t2);
  const float2 O1 = make_float2(t1.x - t3.y, t1.y + t3.x);
  const float2 O3 = make_float2(t1.x + t3.y, t1.y - t3.x);
  const float2 nO1 = make_float2(C * (O1.x - O1.y), C * (O1.x + O1.y));
  const float2 n3O3 = make_float2(-C * (O3.x + O3.y), C * (O3.x - O3.y));
  const float2 iO2 = make_float2(-O2.y, O2.x);
  z[base]         = CADD(E0, O0);
  z[base + 4 * Q] = CSUB(E0, O0);
  z[base + Q]     = CADD(E1, nO1);
  z[base + 5 * Q] = CSUB(E1, nO1);
  z[base + 2 * Q] = CADD(E2, iO2);
  z[base + 6 * Q] = CSUB(E2, iO2);
  z[base + 3 * Q] = CADD(E3, n3O3);
  z[base + 7 * Q] = CSUB(E3, n3O3);
}

// Inverse radix-8 Q=512 stage, PRUNED: only outputs base+{0,Q,2Q,3Q} (< 2048).
__device__ __forceinline__ void inv_r8_q512_top(float2* z,
                                                const float2* __restrict__ tw,
                                                const float2* __restrict__ tw3q,
                                                int tt) {
  const int Q = 512;
  const float C = 0.70710678118654752f;
  const int j = tt & (Q - 1);
  const int base = j;            // tt in [0,512)
  const float2 W1 = tw[4 * Q + j], W2 = tw[2 * Q + j], W4 = tw[Q + j];
  const float4 w35 = *(const float4*)(tw3q + 4 * j);
  const float4 w67 = *(const float4*)(tw3q + 4 * j + 2);
  const float2 W3 = make_float2(w35.x, w35.y);
  const float2 W5 = make_float2(w35.z, w35.w);
  const float2 W6 = make_float2(w67.x, w67.y);
  const float2 W7 = make_float2(w67.z, w67.w);
  const float2 u0 = z[base];
  const float2 u1 = cmulc(z[base + Q], W1);
  const float2 u2 = cmulc(z[base + 2 * Q], W2);
  const float2 u3 = cmulc(z[base + 3 * Q], W3);
  const float2 u4 = cmulc(z[base + 4 * Q], W4);
  const float2 u5 = cmulc(z[base + 5 * Q], W5);
  const float2 u6 = cmulc(z[base + 6 * Q], W6);
  const float2 u7 = cmulc(z[base + 7 * Q], W7);
  const float2 s0 = CADD(u0, u4), s1 = CSUB(u0, u4);
  const float2 s2 = CADD(u2, u6), s3 = CSUB(u2, u6);
  const float2 E0 = CADD(s0, s2), E2 = CSUB(s0, s2);
  const float2 E1 = make_float2(s1.x - s3.y, s1.y + s3.x);
  const float2 E3 = make_float2(s1.x + s3.y, s1.y - s3.x);
  const float2 t0 = CADD(u1, u5), t1 = CSUB(u1, u5);
  const float2 t2 = CADD(u3, u7), t3 = CSUB(u3, u7);
  const float2 O0 = CADD(t0, t2), O2 = CSUB(t0, t2);
  const float2 O1 = make_float2(t1.x - t3.y, t1.y + t3.x);
  const float2 O3 = make_float2(t1.x + t3.y, t1.y - t3.x);
  const float2 nO1 = make_float2(C * (O1.x - O1.y), C * (O1.x + O1.y));
  const float2 n3O3 = make_float2(-C * (O3.x + O3.y), C * (O3.x - O3.y));
  const float2 iO2 = make_float2(-O2.y, O2.x);
  z[base]         = CADD(E0, O0);
  z[base + Q]     = CADD(E1, nO1);
  z[base + 2 * Q] = CADD(E2, iO2);
  z[base + 3 * Q] = CADD(E3, n3O3);
}

// Inverse radix-8 Q=1 stage with the spectral multiply fused into the loads.
__device__ __forceinline__ void inv8_j0_fused(float2* z,
                                              const float2* __restrict__ Xn,
                                              const float2* __restrict__ H1,
                                              const float2* __restrict__ H2,
                                              int b8) {
  const float4* X4 = (const float4*)(Xn + b8);
  const float4* A4 = (const float4*)(H1 + b8);
  const float4* B4 = (const float4*)(H2 + b8);
  float2 u[8];
#pragma unroll
  for (int q = 0; q < 4; ++q) {
    float4 xv = X4[q], av = A4[q], bv = B4[q];
    float2 Cc0 = make_float2(av.x - bv.y, av.y + bv.x);
    float2 Cc1 = make_float2(av.z - bv.w, av.w + bv.z);
    u[2 * q]     = cmul(make_float2(xv.x, xv.y), Cc0);
    u[2 * q + 1] = cmul(make_float2(xv.z, xv.w), Cc1);
  }
  const float C = 0.70710678118654752f;
  const float2 s0 = CADD(u[0], u[4]), s1 = CSUB(u[0], u[4]);
  const float2 s2 = CADD(u[2], u[6]), s3 = CSUB(u[2], u[6]);
  const float2 E0 = CADD(s0, s2), E2 = CSUB(s0, s2);
  const float2 E1 = make_float2(s1.x - s3.y, s1.y + s3.x);
  const float2 E3 = make_float2(s1.x + s3.y, s1.y - s3.x);
  const float2 t0 = CADD(u[1], u[5]), t1 = CSUB(u[1], u[5]);
  const float2 t2 = CADD(u[3], u[7]), t3 = CSUB(u[3], u[7]);
  const float2 O0 = CADD(t0, t2), O2 = CSUB(t0, t2);
  const float2 O1 = make_float2(t1.x - t3.y, t1.y + t3.x);
  const float2 O3 = make_float2(t1.x + t3.y, t1.y - t3.x);
  const float2 nO1 = make_float2(C * (O1.x - O1.y), C * (O1.x + O1.y));
  const float2 n3O3 = make_float2(-C * (O3.x + O3.y), C * (O3.x - O3.y));
  const float2 iO2 = make_float2(-O2.y, O2.x);
  z[b8]     = CADD(E0, O0);
  z[b8 + 4] = CSUB(E0, O0);
  z[b8 + 1] = CADD(E1, nO1);
  z[b8 + 5] = CSUB(E1, nO1);
  z[b8 + 2] = CADD(E2, iO2);
  z[b8 + 6] = CSUB(E2, iO2);
  z[b8 + 3] = CADD(E3, n3O3);
  z[b8 + 7] = CSUB(E3, n3O3);
}

// ---------------------------------------------------------------------------
// Kernel P: twiddles + tw3 + zero out.
// ---------------------------------------------------------------------------
__global__ __launch_bounds__(256) void prep_kernel(float2* __restrict__ tw,
                                                   float2* __restrict__ tw3,
                                                   float* __restrict__ out) {
  const int blk = blockIdx.x;
  const int tid = threadIdx.x;
  if (blk < 16) {
    const int i = blk * 256 + tid;
    if (i == 0) {
      tw[0] = make_float2(1.f, 0.f);
    } else {
      int half = 1 << (31 - __clz(i));
      int j = i - half;
      float ang = -3.14159265358979323846f * (float)j / (float)half;
      float s, c;
      sincosf(ang, &s, &c);
      tw[i] = make_float2(c, s);
    }
    if (i < 3200) out[i] = 0.f;
    return;
  }
  const int u = (blk - 16) * 256 + tid;
  if (u >= TW3_TOT) return;
  int Q, j;
  if (u < TW3_Q8)        { Q = 4;   j = u; }
  else if (u < TW3_Q32)  { Q = 8;   j = u - TW3_Q8; }
  else if (u < TW3_Q64)  { Q = 32;  j = u - TW3_Q32; }
  else if (u < TW3_Q256) { Q = 64;  j = u - TW3_Q64; }
  else if (u < TW3_Q512) { Q = 256; j = u - TW3_Q256; }
  else                   { Q = 512; j = u - TW3_Q512; }
  const float PI = 3.14159265358979323846f;
  float s, c;
  float2 W1, W2, W4;
  if (j == 0) { W1 = W2 = W4 = make_float2(1.f, 0.f); }
  else {
    float jf = (float)j;
    sincosf(-PI * jf / (float)(4 * Q), &s, &c); W1 = make_float2(c, s);
    sincosf(-PI * jf / (float)(2 * Q), &s, &c); W2 = make_float2(c, s);
    sincosf(-PI * jf / (float)(Q),     &s, &c); W4 = make_float2(c, s);
  }
  float2 W3 = cmul(W1, W2);
  float2 W5 = cmul(W1, W4);
  float2 W6 = cmul(W2, W4);
  float2 W7 = cmul(W3, W4);
  float4* o = (float4*)(tw3 + 4 * (size_t)u);
  o[0] = make_float4(W3.x, W3.y, W5.x, W5.y);
  o[1] = make_float4(W6.x, W6.y, W7.x, W7.y);
}

// ---------------------------------------------------------------------------
// Kernel S: forward FFT4096 producers, 512 threads (1 butterfly/thread/stage).
// ---------------------------------------------------------------------------
__global__ __launch_bounds__(512) void specf_kernel(const float* __restrict__ x,
                                                    const float* __restrict__ ker,
                                                    const float2* __restrict__ tw,
                                                    const float2* __restrict__ tw3,
                                                    float2* __restrict__ Hc,
                                                    float2* __restrict__ Xs) {
  __shared__ __align__(16) float2 z[NFFT];
  const int tid = threadIdx.x;
  const int blk = blockIdx.x;
  if (blk < NF) {
    const float* kr = ker + blk * LK;
#pragma unroll
    for (int h = 0; h < 8; ++h) {
      int i = tid + 512 * h;
      float v = 0.f;
      if (i < LK) v = 0.5f * (kr[i] + kr[LK - 1 - i]);   // symmetrize
      z[i] = make_float2(v, 0.f);
    }
  } else {
    const float* xr = x + (size_t)(blk - NF) * TT;
#pragma unroll
    for (int h = 0; h < 8; ++h) {
      int i = tid + 512 * h;
      float v = 0.f;
      if (i < 2816) {                 // window index i -> original i-384
        int m = i - 384;
        if (m < 0) m = -m;            // reflect (edge excluded)
        if (m > 2047) m = 4094 - m;
        v = xr[m];
      }
      z[i] = make_float2(v, 0.f);
    }
  }
  __syncthreads();
  fwd_r8(z, tw, tw3 + 4 * TW3_Q512, tid, 512);
  __syncthreads();
  fwd_r8(z, tw, tw3 + 4 * TW3_Q64, tid, 64);
  __builtin_amdgcn_wave_barrier();
  fwd_r8(z, tw, tw3 + 4 * TW3_Q8, tid, 8);
  __builtin_amdgcn_wave_barrier();
  fwd_r8_j0(z, tid << 3);
  __syncthreads();
  if (blk < NF) {
    const float s = 1.0f / 4096.0f;   // fold IFFT4096 normalization into Hc
    float2* o = Hc + (size_t)blk * NFFT;
#pragma unroll
    for (int h = 0; h < 8; ++h) {
      int i = tid + 512 * h;
      float2 v = z[i];
      o[i] = make_float2(v.x * s, -v.y * s);   // conj
    }
  } else {
    float2* o = Xs + (size_t)(blk - NF) * NFFT;
#pragma unroll
    for (int h = 0; h < 8; ++h) {
      int i = tid + 512 * h;
      o[i] = z[i];
    }
  }
}

// ---------------------------------------------------------------------------
// Kernel A: frequency-domain conv + Hilbert. R5: the fwd-r4 / Hilbert-mask /
// inv-r4 middle is FUSED register-resident (each thread's group [4bf,4bf+4)
// is closed under all three ops); LDS grab/epilogue reads widened to b128.
// Arithmetic on the surviving path is literally identical (incl. the exact
// +0 adds the old masked-LDS produced) -> bit-identical output.
// ---------------------------------------------------------------------------
__global__ __launch_bounds__(256) void convhil_kernel(const float2* __restrict__ Xs,
                                                      const float2* __restrict__ Hc,
                                                      const float2* __restrict__ tw,
                                                      const float2* __restrict__ tw3,
                                                      unsigned short* __restrict__ amps,
                                                      unsigned int* __restrict__ binp) {
  __shared__ __align__(16) float2 z[NFFT];   // 32 KB
  const int tid = threadIdx.x;
  const int wv = tid >> 6;
  const int lane = tid & 63;
  const int ord = blockIdx.x;
  const int p = ord / NS;
  const int n = ord % NS;
  const int o1 = p;                          // pha band
  const int o2 = 10 + (9 - p);               // amp band (short with long)
  const float2* Xn = Xs + (size_t)n * NFFT;
  const float2* H1 = Hc + (size_t)o1 * NFFT;
  const float2* H2 = Hc + (size_t)o2 * NFFT;
  // ---- fused spectral-mult + inverse Q=1 stage ----
  inv8_j0_fused(z, Xn, H1, H2, tid << 3);
  inv8_j0_fused(z, Xn, H1, H2, (tid + 256) << 3);
  __builtin_amdgcn_wave_barrier();
  inv_r8(z, tw, tw3 + 4 * TW3_Q8, tid, 8);
  inv_r8(z, tw, tw3 + 4 * TW3_Q8, tid + 256, 8);
  __builtin_amdgcn_wave_barrier();
  inv_r8(z, tw, tw3 + 4 * TW3_Q64, tid, 64);
  inv_r8(z, tw, tw3 + 4 * TW3_Q64, tid + 256, 64);
  __syncthreads();
  inv_r8_q512_top(z, tw, tw3 + 4 * TW3_Q512, tid);
  inv_r8_q512_top(z, tw, tw3 + 4 * TW3_Q512, tid + 256);
  __syncthreads();
  // ---- grab y1,y2 into registers (b128 reads; bA is 32B-aligned) ----
  const int bA = 4 * tid;
  const int bB = 1024 + 4 * tid;
  const float4 gA0 = *(const float4*)&z[bA];
  const float4 gA1 = *(const float4*)&z[bA + 2];
  const float4 gB0 = *(const float4*)&z[bB];
  const float4 gB1 = *(const float4*)&z[bB + 2];
  float acc1A[4] = {gA0.x, gA0.z, gA1.x, gA1.z};
  float acc2A[4] = {gA0.y, gA0.w, gA1.y, gA1.w};
  float acc1B[4] = {gB0.x, gB0.z, gB1.x, gB1.z};
  float acc2B[4] = {gB0.y, gB0.w, gB1.y, gB1.w};
  __syncthreads();                                    // barrier 3
  // ---- forward radix-8 stage Q=256 (cross-wave) ----
  fwd_r8(z, tw, tw3 + 4 * TW3_Q256, tid, 256);
  __syncthreads();                                    // barrier 4
  // ---- forward radix-8 stages Q=32, Q=4 (wave-local) ----
  fwd_r8(z, tw, tw3 + 4 * TW3_Q32, tid, 32);
  __builtin_amdgcn_wave_barrier();
  fwd_r8(z, tw, tw3 + 4 * TW3_Q4, tid, 4);
  __builtin_amdgcn_wave_barrier();
  // ---- FUSED fwd-r4 + Hilbert mask + inv-r4 (register-resident) ----
#pragma unroll
  for (int h = 0; h < 2; ++h) {
    const int bf = 128 * wv + lane + 64 * h;
    const int base = bf << 2;
    const float2 x0 = z[base], x1 = z[base + 1];
    const float2 x2 = z[base + 2], x3 = z[base + 3];
    const float2 t0 = CADD(x0, x2), t1 = CSUB(x0, x2);
    const float2 t2 = CADD(x1, x3), t3 = CSUB(x1, x3);
    const float2 o0 = CADD(t0, t2);
    const float2 o1 = make_float2(t1.x + t3.y, t1.y - t3.x);
    const float2 o2 = CSUB(t0, t2);
    // mask on pp = 4bf+{0,1,2,3}: pp0 double (keep if bf==0); pp1 double;
    // pp2 zero (keep if bf==0); pp3 zero.  (o3 was computed-then-zeroed
    // in the old code -> value unused -> not computed here.)
    float2 m0, m2;
    if (bf == 0) { m0 = o0; m2 = o2; }
    else {
      m0 = make_float2(2.f * o0.x, 2.f * o0.y);
      m2 = make_float2(0.f, 0.f);
    }
    const float2 m1 = make_float2(2.f * o1.x, 2.f * o1.y);
    const float2 m3 = make_float2(0.f, 0.f);
    // inverse radix-4 (identical ops to old LDS version, incl +0 adds)
    const float2 T0 = CADD(m0, m2), T1 = CSUB(m0, m2);
    const float2 T2 = CADD(m1, m3), T3 = CSUB(m1, m3);
    z[base]     = CADD(T0, T2);
    z[base + 1] = make_float2(T1.x - T3.y, T1.y + T3.x);
    z[base + 2] = CSUB(T0, T2);
    z[base + 3] = make_float2(T1.x + T3.y, T1.y - T3.x);
  }
  __builtin_amdgcn_wave_barrier();
  // ---- inverse radix-8 stages Q=4, Q=32 (wave-local) ----
  inv_r8(z, tw, tw3 + 4 * TW3_Q4, tid, 4);
  __builtin_amdgcn_wave_barrier();
  inv_r8(z, tw, tw3 + 4 * TW3_Q32, tid, 32);
  __builtin_amdgcn_wave_barrier();
  __syncthreads();                                    // barrier 5
  // ---- inverse radix-8 stage Q=256 (cross-wave) ----
  inv_r8(z, tw, tw3 + 4 * TW3_Q256, tid, 256);
  __syncthreads();                                    // barrier 6
  // ---- epilogue: bins for o1, pre-split amp for o2 (b128 reads) ----
  unsigned int* bp = binp + ((size_t)n * 10 + o1) * 512;
  const int rid = n * 10 + (o2 - 10);
  unsigned short* ap = amps + (size_t)rid * (TT * 3);
  const int offA = (tid >> 1) * 24 + (tid & 1) * 4;          // t-group tid/2
  const int offB = (128 + (tid >> 1)) * 24 + (tid & 1) * 4;  // t-group 128+tid/2
  const float invN = 1.0f / 2048.0f;
  const float4 eA0 = *(const float4*)&z[bA];
  const float4 eA1 = *(const float4*)&z[bA + 2];
  const float4 eB0 = *(const float4*)&z[bB];
  const float4 eB1 = *(const float4*)&z[bB + 2];
  const float wAx[4] = {eA0.x, eA0.z, eA1.x, eA1.z};
  const float wAy[4] = {eA0.y, eA0.w, eA1.y, eA1.w};
  const float wBx[4] = {eB0.x, eB0.z, eB1.x, eB1.z};
  const float wBy[4] = {eB0.y, eB0.w, eB1.y, eB1.w};
  us4 hA, mA, lA, hB, mB, lB;
  unsigned int dA = 0, dB = 0;
#pragma unroll
  for (int r = 0; r < 4; ++r) {
    float h1 = wAy[r] * invN - acc2A[r];
    float h2 = acc1A[r] - wAx[r] * invN;
    float phA = atan2f(h1, acc1A[r]);
    float vA = sqrtf(fmaf(acc2A[r], acc2A[r], h2 * h2));
    int b = (int)floorf((phA + 3.14159274f) / 6.2831855f * 18.0f);
    b = b < 0 ? 0 : (b > 17 ? 17 : b);
    dA |= ((unsigned int)b) << (8 * r);
    float g1 = wBy[r] * invN - acc2B[r];
    float g2 = acc1B[r] - wBx[r] * invN;
    float phB = atan2f(g1, acc1B[r]);
    float vB = sqrtf(fmaf(acc2B[r], acc2B[r], g2 * g2));
    int b2 = (int)floorf((phB + 3.14159274f) / 6.2831855f * 18.0f);
    b2 = b2 < 0 ? 0 : (b2 > 17 ? 17 : b2);
    dB |= ((unsigned int)b2) << (8 * r);
    // ---- 3-way exact bf16 split (bit-identical to original mi code) ----
    {
      unsigned int u = __float_as_uint(vA);
      float hf = __uint_as_float(u & 0xFFFF0000u);
      float r1 = vA - hf;
      unsigned int u2 = __float_as_uint(r1);
      float md = __uint_as_float(u2 & 0xFFFF0000u);
      float r2 = r1 - md;
      unsigned int u3 = __float_as_uint(r2);
      hA[r] = (unsigned short)(u >> 16);
      mA[r] = (unsigned short)(u2 >> 16);
      lA[r] = (unsigned short)(u3 >> 16);
    }
    {
      unsigned int u = __float_as_uint(vB);
      float hf = __uint_as_float(u & 0xFFFF0000u);
      float r1 = vB - hf;
      unsigned int u2 = __float_as_uint(r1);
      float md = __uint_as_float(u2 & 0xFFFF0000u);
      float r2 = r1 - md;
      unsigned int u3 = __float_as_uint(r2);
      hB[r] = (unsigned short)(u >> 16);
      mB[r] = (unsigned short)(u2 >> 16);
      lB[r] = (unsigned short)(u3 >> 16);
    }
  }
  bp[tid] = dA;
  bp[tid + 256] = dB;
  *(us4*)(ap + offA)      = hA;
  *(us4*)(ap + offA + 8)  = mA;
  *(us4*)(ap + offA + 16) = lA;
  *(us4*)(ap + offB)      = hB;
  *(us4*)(ap + offB + 8)  = mB;
  *(us4*)(ap + offB + 16) = lB;
}

// ---------------------------------------------------------------------------
// Kernel C: binned MI via MFMA. R5: idx pair reads as b64; staging as uint2.
// ---------------------------------------------------------------------------
__global__ __launch_bounds__(256) void mi_kernel(const unsigned short* __restrict__ amps,
                                                 const unsigned int* __restrict__ binp,
                                                 float* __restrict__ out) {
  __shared__ __align__(16) unsigned int idxA[512], idxB[512];
  __shared__ float Cp[2][4][12][19];
  const int tid = threadIdx.x;
  const int wave = tid >> 6;
  const int lane = tid & 63;
  const int bid = blockIdx.x;
  const int blk = (bid & 7) * 80 + (bid >> 3);
  const int bc = blk / 20, r = blk % 20;
  const int jpA = r, jpB = r + 20;           // same (jp & 3) => same ja
  const unsigned int* bpA =
      binp + ((size_t)(bc * 4 + jpA / 10) * 10 + (jpA % 10)) * 512;
  const unsigned int* bpB =
      binp + ((size_t)(bc * 4 + jpB / 10) * 10 + (jpB % 10)) * 512;
  *(uint2*)&idxA[2 * tid] = *(const uint2*)&bpA[2 * tid];
  *(uint2*)&idxB[2 * tid] = *(const uint2*)&bpB[2 * tid];
  __syncthreads();
  const int n16 = lane & 15;    // A row m / B col n / C col
  const int quad = lane >> 4;   // k-quad (0..3)
  const int aband = n16 < 10 ? n16 : 9;
  const int ja = (jpA & 3) + 4 * aband;   // identical for jpB
  const int nsig = bc * 4 + ja / 10;
  const int rid = nsig * 10 + (ja % 10);
  const unsigned short* aptr = amps + (size_t)rid * (TT * 3) + quad * 24;
  const bool isAmp = (n16 < 10);
  const bool isOne = (n16 == 10);
  const int tgt1 = n16 < 2 ? n16 + 16 : (n16 < 4 ? n16 + 14 : 255);
  const bool useA1 = (n16 < 2);
  short8 aOne, aZero;
#pragma unroll
  for (int j = 0; j < 8; ++j) {
    aOne[j] = isOne ? (short)0x3F80 : (short)0;
    aZero[j] = 0;
  }
  f32x4 accA0 = {0.f, 0.f, 0.f, 0.f};
  f32x4 accB0 = {0.f, 0.f, 0.f, 0.f};
  f32x4 accC1 = {0.f, 0.f, 0.f, 0.f};
  const int s0 = wave * 16, s1 = s0 + 16;
  for (int s = s0; s < s1; ++s) {
    short8 ah, amv, alv;
    if (isAmp) {
      const unsigned short* g = aptr + s * 96;
      ah  = *(const short8*)(g);
      amv = *(const short8*)(g + 8);
      alv = *(const short8*)(g + 16);
    } else {
      ah = aOne; amv = aZero; alv = aZero;
    }
    const int dw = s * 8 + quad * 2;
    const uint2 dAp = *(const uint2*)&idxA[dw];
    const uint2 dBp = *(const uint2*)&idxB[dw];
    short8 bA0, bB0, bC1;
#pragma unroll
    for (int j = 0; j < 8; ++j) {
      unsigned int byA = ((j < 4 ? dAp.x : dAp.y) >> ((j & 3) * 8)) & 0xFFu;
      unsigned int byB = ((j < 4 ? dBp.x : dBp.y) >> ((j & 3) * 8)) & 0xFFu;
      bA0[j] = (byA == (unsigned int)n16) ? (short)0x3F80 : (short)0;
      bB0[j] = (byB == (unsigned int)n16) ? (short)0x3F80 : (short)0;
      unsigned int byC = useA1 ? byA : byB;
      bC1[j] = (byC == (unsigned int)tgt1) ? (short)0x3F80 : (short)0;
    }
    accA0 = __builtin_amdgcn_mfma_f32_16x16x32_bf16(ah,  bA0, accA0, 0, 0, 0);
    accA0 = __builtin_amdgcn_mfma_f32_16x16x32_bf16(amv, bA0, accA0, 0, 0, 0);
    accA0 = __builtin_amdgcn_mfma_f32_16x16x32_bf16(alv, bA0, accA0, 0, 0, 0);
    accB0 = __builtin_amdgcn_mfma_f32_16x16x32_bf16(ah,  bB0, accB0, 0, 0, 0);
    accB0 = __builtin_amdgcn_mfma_f32_16x16x32_bf16(amv, bB0, accB0, 0, 0, 0);
    accB0 = __builtin_amdgcn_mfma_f32_16x16x32_bf16(alv, bB0, accB0, 0, 0, 0);
    accC1 = __builtin_amdgcn_mfma_f32_16x16x32_bf16(ah,  bC1, accC1, 0, 0, 0);
    accC1 = __builtin_amdgcn_mfma_f32_16x16x32_bf16(amv, bC1, accC1, 0, 0, 0);
    accC1 = __builtin_amdgcn_mfma_f32_16x16x32_bf16(alv, bC1, accC1, 0, 0, 0);
  }
#pragma unroll
  for (int rr = 0; rr < 4; ++rr) {
    int row = quad * 4 + rr;
    if (row < 11) {
      Cp[0][wave][row][n16] = accA0[rr];
      Cp[1][wave][row][n16] = accB0[rr];
      if (n16 < 2)      Cp[0][wave][row][16 + n16] = accC1[rr];
      else if (n16 < 4) Cp[1][wave][row][14 + n16] = accC1[rr];
    }
  }
  __syncthreads();
  int pl = -1, a_ = 0, jp_ = 0;
  if (tid < 10) { pl = 0; a_ = tid; jp_ = jpA; }
  else if (tid >= 64 && tid < 74) { pl = 1; a_ = tid - 64; jp_ = jpB; }
  if (pl >= 0) {
    float tot = 0.f, mb_[18];
#pragma unroll
    for (int b = 0; b < 18; ++b) {
      float s = Cp[pl][0][a_][b] + Cp[pl][1][a_][b] + Cp[pl][2][a_][b] + Cp[pl][3][a_][b];
      float c = Cp[pl][0][10][b] + Cp[pl][1][10][b] + Cp[pl][2][10][b] + Cp[pl][3][10][b];
      float mb = s / fmaxf(c, 1.0f);
      mb_[b] = mb; tot += mb;
    }
    tot = fmaxf(tot, 1e-12f);
    float s = 0.f;
#pragma unroll
    for (int b = 0; b < 18; ++b) {
      float pb = mb_[b] / tot;
      s += pb * logf(fmaxf(pb, 1e-12f));
    }
    const float LOGN = 2.8903717578961645f; // log(18)
    atomicAdd(&out[bc * 100 + (jp_ >> 2) * 10 + a_],
              0.25f * (LOGN + s) / LOGN);
  }
}

extern "C" void kernel_launch(void* const* d_in, const int* in_sizes, int n_in,
                              void* d_out, int out_size, void* d_ws, size_t ws_size,
                              hipStream_t stream) {
  (void)in_sizes; (void)n_in; (void)out_size; (void)ws_size;
  const float* x = (const float*)d_in[0];     // (4,8,4,2048) fp32
  const float* ker = (const float*)d_in[1];   // (20,769) fp32
  float* out = (float*)d_out;                 // 3200 fp32
  unsigned short* amps = (unsigned short*)d_ws;          // 128*10*2048*3 ushorts (~15.7 MB)
  float2* tw  = (float2*)(amps + (size_t)NS * 10 * TT * 3);
  float2* tw3 = tw + NFFT;                    // 876*4 float2 (~28 KB)
  float2* Hc  = tw3 + 4 * TW3_TOT;            // 20*4096 float2 (~655 KB)
  float2* Xs  = Hc + (size_t)NF * NFFT;       // 128*4096 float2 (~4.2 MB)
  unsigned int* binp = (unsigned int*)(Xs + (size_t)NS * NFFT);  // 128*10*512 dwords

  prep_kernel<<<20, 256, 0, stream>>>(tw, tw3, out);
  specf_kernel<<<NF + NS, 512, 0, stream>>>(x, ker, tw, tw3, Hc, Xs);
  convhil_kernel<<<NS * 10, 256, 0, stream>>>(Xs, Hc, tw, tw3, amps, binp);
  mi_kernel<<<640, 256, 0, stream>>>(amps, binp, out);
}